// Round 1
// baseline (870.121 us; speedup 1.0000x reference)
//
#include <hip/hip_runtime.h>
#include <hip/hip_cooperative_groups.h>
#include <cmath>

namespace cg = cooperative_groups;

#define B_ 16
#define N_ 48
#define HID_ 64
#define NL_ 128
#define NNODE_ (B_*N_)        // 768
#define NEDGE_ (B_*N_*N_)     // 36864
#define GRID_ 768

__device__ __forceinline__ float sigmoidf_(float x){ return 1.0f/(1.0f+expf(-x)); }

// ===========================================================================
// Cooperative single-kernel path
// ===========================================================================
struct KParams {
    const float *g, *h0, *e;
    const float *mw0, *mb0, *mw1, *mb1, *mw2, *mb2;
    const float *wih, *whh, *bih, *bhh;
    const float *r0w0, *r0b0, *r0w1, *r0b1, *r0w2, *r0b2;
    const float *r1w0, *r1b0, *r1w1, *r1b1, *r1w2, *r1b2;
    float *A, *Bm, *Ab, *Bb, *hfirst, *hA, *hB, *mask, *wihT, *whhT, *part, *relu2, *out;
};

// readout MLP layer: Xs [4][128] in LDS, W/bias in global (L1/L2-hot)
__device__ __forceinline__ void rd_layer_g(
    const float* __restrict__ Xs, const float* __restrict__ W,
    const float* __restrict__ bias, float* __restrict__ Ys,
    int dim, int o, int ng, bool do_relu)
{
    float a0 = bias[o];
    float a1 = a0;
    for (int i = 0; i < dim; i += 4){
        float w0 = W[(size_t)(i+0)*128 + o];
        float w1 = W[(size_t)(i+1)*128 + o];
        float w2 = W[(size_t)(i+2)*128 + o];
        float w3 = W[(size_t)(i+3)*128 + o];
        const float4 x0 = *(const float4*)&Xs[ng*128 + i];
        const float4 x1 = *(const float4*)&Xs[(ng+2)*128 + i];
        a0 += x0.x*w0 + x0.y*w1 + x0.z*w2 + x0.w*w3;
        a1 += x1.x*w0 + x1.y*w1 + x1.z*w2 + x1.w*w3;
    }
    if (do_relu){ a0 = fmaxf(a0, 0.f); a1 = fmaxf(a1, 0.f); }
    Ys[ng*128 + o] = a0;
    Ys[(ng+2)*128 + o] = a1;
}

// LDS layout (floats), total 8032 = 32128 B -> 4 blocks/CU by LDS, need 3.
//  [0, 6336)  : phase0 x1s (48*132) | layers r2s (48*128) | readout xs/ys/zs/os0
//  [6336,6560): persist: gs[48] hs[64] wAs[48] wBs[48] sAB[2] (+pad)
//  [6560,8032): layer scratch pU[256] pV[256] Us[128] Vs[128] pC[256] aggs[64] gi[192] gh[192]
__global__ __launch_bounds__(256, 3) void k_all(KParams p)
{
    __shared__ __align__(16) float smem[8032];
    cg::grid_group grid = cg::this_grid();
    const int tid  = threadIdx.x;
    const int bj   = blockIdx.x;
    const int b    = bj / 48, j = bj - b*48;
    const int base = b*48;

    // ---------------- phase 0a: prep (flat index over 768*256 threads) -----
    {
        int idx = bj*256 + tid;
        if (idx < 24576) {
            int r = idx >> 13;          // 0..2
            int c = (idx >> 6) & 127;
            int m = idx & 63;
            int t = 48 - 16*r;
            const float* src = p.mw2 + c*4096 + m*64;
            float a = 0.f, bb = 0.f;
            for (int k = 0; k < 64; k++){ float v = src[k]; if (k < t) a += v; else bb += v; }
            p.A[idx] = a; p.Bm[idx] = bb;
        } else if (idx < 24768) {
            int i2 = idx - 24576;
            int r = i2 >> 6, m = i2 & 63;
            int t = 48 - 16*r;
            const float* src = p.mb2 + m*64;
            float a = 0.f, bb = 0.f;
            for (int k = 0; k < 64; k++){ float v = src[k]; if (k < t) a += v; else bb += v; }
            p.Ab[i2] = a; p.Bb[i2] = bb;
        } else if (idx < 73920) {
            int i3 = idx - 24768;
            int node = i3 >> 6, m = i3 & 63;
            p.hfirst[i3] = (m < 32) ? p.h0[node*32 + m] : 0.f;
            if (m == 0) {
                float s = 0.f;
                for (int k = 0; k < 32; k++) s += p.h0[node*32 + k];
                p.mask[node] = (s > 0.f) ? 1.f : 0.f;
            }
        } else if (idx < 98496) {
            int i4 = idx - 73920;
            if (i4 < 12288) {
                int k = i4 / 192, col = i4 - k*192;
                p.wihT[i4] = p.wih[col*64 + k];
            } else {
                int i5 = i4 - 12288;
                int k = i5 / 192, col = i5 - k*192;
                p.whhT[i5] = p.whh[col*64 + k];
            }
        }
    }

    // ---------------- phase 0b: edge MLP, 48 edges per block ----------------
    {
        float* x1s = smem;                    // stride 132
        const int et = tid & 15;
        const int o0 = (tid >> 4) * 8;
        const size_t e0 = (size_t)bj * 48;

        float acc[3][8];
        {
            float4 ba = *(const float4*)&p.mb0[o0];
            float4 bb = *(const float4*)&p.mb0[o0 + 4];
            #pragma unroll
            for (int q = 0; q < 3; q++){
                acc[q][0]=ba.x; acc[q][1]=ba.y; acc[q][2]=ba.z; acc[q][3]=ba.w;
                acc[q][4]=bb.x; acc[q][5]=bb.y; acc[q][6]=bb.z; acc[q][7]=bb.w;
            }
        }
        #pragma unroll
        for (int i4 = 0; i4 < 4; i4++){
            float4 ev[3];
            #pragma unroll
            for (int q = 0; q < 3; q++)
                ev[q] = *(const float4*)&p.e[(e0 + q*16 + et)*16 + i4*4];
            #pragma unroll
            for (int d = 0; d < 4; d++){
                int i = i4*4 + d;
                float4 wa = *(const float4*)&p.mw0[i*128 + o0];
                float4 wb = *(const float4*)&p.mw0[i*128 + o0 + 4];
                #pragma unroll
                for (int q = 0; q < 3; q++){
                    float xi = (d==0) ? ev[q].x : (d==1) ? ev[q].y : (d==2) ? ev[q].z : ev[q].w;
                    acc[q][0] += xi*wa.x; acc[q][1] += xi*wa.y;
                    acc[q][2] += xi*wa.z; acc[q][3] += xi*wa.w;
                    acc[q][4] += xi*wb.x; acc[q][5] += xi*wb.y;
                    acc[q][6] += xi*wb.z; acc[q][7] += xi*wb.w;
                }
            }
        }
        #pragma unroll
        for (int q = 0; q < 3; q++){
            int el = q*16 + et;
            *(float4*)&x1s[el*132 + o0] =
                make_float4(fmaxf(acc[q][0],0.f), fmaxf(acc[q][1],0.f),
                            fmaxf(acc[q][2],0.f), fmaxf(acc[q][3],0.f));
            *(float4*)&x1s[el*132 + o0 + 4] =
                make_float4(fmaxf(acc[q][4],0.f), fmaxf(acc[q][5],0.f),
                            fmaxf(acc[q][6],0.f), fmaxf(acc[q][7],0.f));
        }
        __syncthreads();

        float a2[3][8];
        {
            float4 ba = *(const float4*)&p.mb1[o0];
            float4 bb = *(const float4*)&p.mb1[o0 + 4];
            #pragma unroll
            for (int q = 0; q < 3; q++){
                a2[q][0]=ba.x; a2[q][1]=ba.y; a2[q][2]=ba.z; a2[q][3]=ba.w;
                a2[q][4]=bb.x; a2[q][5]=bb.y; a2[q][6]=bb.z; a2[q][7]=bb.w;
            }
        }
        // layer 2: read mw1 rows directly (w1[i][o]) -> no transpose needed,
        // same per-accumulator summation order as the w1T version.
        for (int i4 = 0; i4 < 32; i4++){
            int i = i4*4;
            float4 w0a = *(const float4*)&p.mw1[(size_t)(i+0)*128 + o0];
            float4 w0b = *(const float4*)&p.mw1[(size_t)(i+0)*128 + o0 + 4];
            float4 w1a = *(const float4*)&p.mw1[(size_t)(i+1)*128 + o0];
            float4 w1b = *(const float4*)&p.mw1[(size_t)(i+1)*128 + o0 + 4];
            float4 w2a = *(const float4*)&p.mw1[(size_t)(i+2)*128 + o0];
            float4 w2b = *(const float4*)&p.mw1[(size_t)(i+2)*128 + o0 + 4];
            float4 w3a = *(const float4*)&p.mw1[(size_t)(i+3)*128 + o0];
            float4 w3b = *(const float4*)&p.mw1[(size_t)(i+3)*128 + o0 + 4];
            float4 xv[3];
            #pragma unroll
            for (int q = 0; q < 3; q++)
                xv[q] = *(const float4*)&x1s[(q*16 + et)*132 + i];
            #pragma unroll
            for (int q = 0; q < 3; q++){
                float4 x = xv[q];
                a2[q][0] += x.x*w0a.x + x.y*w1a.x + x.z*w2a.x + x.w*w3a.x;
                a2[q][1] += x.x*w0a.y + x.y*w1a.y + x.z*w2a.y + x.w*w3a.y;
                a2[q][2] += x.x*w0a.z + x.y*w1a.z + x.z*w2a.z + x.w*w3a.z;
                a2[q][3] += x.x*w0a.w + x.y*w1a.w + x.z*w2a.w + x.w*w3a.w;
                a2[q][4] += x.x*w0b.x + x.y*w1b.x + x.z*w2b.x + x.w*w3b.x;
                a2[q][5] += x.x*w0b.y + x.y*w1b.y + x.z*w2b.y + x.w*w3b.y;
                a2[q][6] += x.x*w0b.z + x.y*w1b.z + x.z*w2b.z + x.w*w3b.z;
                a2[q][7] += x.x*w0b.w + x.y*w1b.w + x.z*w2b.w + x.w*w3b.w;
            }
        }
        #pragma unroll
        for (int q = 0; q < 3; q++){
            size_t ee = e0 + q*16 + et;
            *(float4*)&p.relu2[ee*128 + o0] =
                make_float4(fmaxf(a2[q][0],0.f), fmaxf(a2[q][1],0.f),
                            fmaxf(a2[q][2],0.f), fmaxf(a2[q][3],0.f));
            *(float4*)&p.relu2[ee*128 + o0 + 4] =
                make_float4(fmaxf(a2[q][4],0.f), fmaxf(a2[q][5],0.f),
                            fmaxf(a2[q][6],0.f), fmaxf(a2[q][7],0.f));
        }
    }
    grid.sync();   // relu2 + all prep outputs visible

    // ---------------- layers: carve LDS ----------------
    float* r2s  = smem;          // 48*128, persists across all 3 layers
    float* gs   = smem + 6336;   // 48, persists
    float* hs   = smem + 6384;   // 64
    float* wAs  = smem + 6448;   // 48
    float* wBs  = smem + 6496;   // 48
    float* sAB  = smem + 6544;   // 2
    float* pU   = smem + 6560;   // 2*128
    float* pV   = smem + 6816;   // 2*128
    float* Us   = smem + 7072;   // 128
    float* Vs   = smem + 7200;   // 128
    float* pC   = smem + 7328;   // 4*64
    float* aggs = smem + 7584;   // 64
    float* gi   = smem + 7648;   // 192
    float* gh   = smem + 7840;   // 192

    // load this block's relu2 column-slice ONCE (reused by all 3 layers)
    for (int idx = tid; idx < 48*128; idx += 256){
        int i = idx >> 7, c = idx & 127;
        r2s[idx] = p.relu2[((size_t)(base + i)*48 + j)*128 + c];
    }
    if (tid < 48) gs[tid] = p.g[(size_t)(base + tid)*48 + j];
    __syncthreads();

    const int r  = j % 3;
    const int q0 = j + j/3;

    for (int L = 0; L < 3; L++){
        const float* hin = (L==0) ? p.hfirst : (L==1) ? p.hA : p.hB;
        float*      hout = (L==1) ? p.hB : p.hA;

        if (tid < 64) hs[tid] = hin[(size_t)bj*64 + tid];
        else if (tid < 112){
            int i = tid - 64;
            wAs[i] = gs[i] * hin[(size_t)(base+i)*64 + q0];
            wBs[i] = gs[i] * hin[(size_t)(base+i)*64 + q0 + 1];
        }
        __syncthreads();
        if (tid < 2){
            const float* src = tid ? wBs : wAs;
            float s = 0.f;
            for (int i = 0; i < 48; i++) s += src[i];
            sAB[tid] = s;
        }
        {   // U/V partials from LDS-cached relu2 (same 2x24 order as before)
            int c = tid & 127, half = tid >> 7;
            const float* rb = r2s + c;
            float aU = 0.f, aV = 0.f;
            for (int ii = 0; ii < 24; ii++){
                int i = half*24 + ii;
                float v = rb[i*128];
                aU += wAs[i]*v; aV += wBs[i]*v;
            }
            pU[half*128 + c] = aU; pV[half*128 + c] = aV;
        }
        __syncthreads();
        if (tid < 128) Us[tid] = pU[tid] + pU[128 + tid];
        else { int c = tid - 128; Vs[c] = pV[c] + pV[128 + c]; }
        __syncthreads();
        {   // agg = U@A_r + V@B_r
            int m = tid & 63, cg2 = tid >> 6;
            const float* Arp = p.A  + r*8192 + m;
            const float* Brp = p.Bm + r*8192 + m;
            float a = 0.f;
            for (int cc = 0; cc < 32; cc++){
                int c = cg2*32 + cc;
                a += Us[c]*Arp[c*64] + Vs[c]*Brp[c*64];
            }
            pC[cg2*64 + m] = a;
        }
        __syncthreads();
        if (tid < 64){
            aggs[tid] = pC[tid] + pC[64+tid] + pC[128+tid] + pC[192+tid]
                      + sAB[0]*p.Ab[r*64 + tid] + sAB[1]*p.Bb[r*64 + tid];
        }
        __syncthreads();
        if (tid < 192){
            float gacc = p.bih[tid], hacc = p.bhh[tid];
            for (int k = 0; k < 64; k++){
                gacc += aggs[k] * p.wihT[k*192 + tid];
                hacc += hs[k]   * p.whhT[k*192 + tid];
            }
            gi[tid] = gacc; gh[tid] = hacc;
        }
        __syncthreads();
        if (tid < 64){
            float rr = sigmoidf_(gi[tid] + gh[tid]);
            float zz = sigmoidf_(gi[64+tid] + gh[64+tid]);
            float nn = tanhf(gi[128+tid] + rr*gh[128+tid]);
            float hnew = (1.f - zz)*nn + zz*hs[tid];
            hout[(size_t)bj*64 + tid] = p.mask[bj] * hnew;
        }
        grid.sync();
    }

    // ---------------- readout: 192 blocks (j%4==0), 4 nodes each ------------
    if ((j & 3) == 0){
        int gg = j >> 2;                 // 0..11
        int node0 = base + gg*4;
        float* xs  = smem;               // r2s no longer needed
        float* ys2 = smem + 512;
        float* zs2 = smem + 1024;
        float* os0 = smem + 1536;
        float* mS  = pU;                 // 4 floats, scratch unused now
        int o = tid & 127, ng = tid >> 7;
        if (tid < 4) mS[tid] = p.mask[node0 + tid];
        for (int i = tid; i < 4*128; i += 256){
            int rr = i >> 7, c = i & 127;
            xs[i] = (c < 64) ? p.hfirst[(size_t)(node0+rr)*64 + c]
                             : p.hA[(size_t)(node0+rr)*64 + (c - 64)];
        }
        __syncthreads();
        rd_layer_g(xs,      p.r0w0, p.r0b0, ys2, 128, o, ng, true);  __syncthreads();
        rd_layer_g(ys2,     p.r0w1, p.r0b1, zs2, 128, o, ng, true);  __syncthreads();
        rd_layer_g(zs2,     p.r0w2, p.r0b2, os0, 128, o, ng, false); __syncthreads();
        rd_layer_g(xs + 64, p.r1w0, p.r1b0, ys2, 64,  o, ng, true);  __syncthreads();
        rd_layer_g(ys2,     p.r1w1, p.r1b1, zs2, 128, o, ng, true);  __syncthreads();
        {
            float a0 = p.r1b2[o];
            float a1 = a0;
            for (int i = 0; i < 128; i += 4){
                float w0 = p.r1w2[(size_t)(i+0)*128 + o];
                float w1 = p.r1w2[(size_t)(i+1)*128 + o];
                float w2 = p.r1w2[(size_t)(i+2)*128 + o];
                float w3 = p.r1w2[(size_t)(i+3)*128 + o];
                const float4 x0 = *(const float4*)&zs2[ng*128 + i];
                const float4 x1 = *(const float4*)&zs2[(ng+2)*128 + i];
                a0 += x0.x*w0 + x0.y*w1 + x0.z*w2 + x0.w*w3;
                a1 += x1.x*w0 + x1.y*w1 + x1.z*w2 + x1.w*w3;
            }
            float s = mS[ng]   * os0[ng*128 + o]     * a0
                    + mS[ng+2] * os0[(ng+2)*128 + o] * a1;
            __syncthreads();
            ys2[ng*128 + o] = s;
        }
        __syncthreads();
        if (tid < 128)
            p.part[(size_t)(b*12 + gg)*128 + tid] = ys2[tid] + ys2[128 + tid];
    }
    grid.sync();

    // ---------------- final: 16 blocks (j==0) reduce + sigmoid --------------
    if (j == 0 && tid < 128){
        float s = 0.f;
        for (int c = 0; c < 12; c++) s += p.part[(size_t)(b*12 + c)*128 + tid];
        p.out[(size_t)b*128 + tid] = 1.0f / (1.0f + expf(-s));
    }
}

// ===========================================================================
// Fallback path: previous verified 7-kernel pipeline (unchanged)
// ===========================================================================
__global__ void k_prep(const float* __restrict__ w2, const float* __restrict__ b2,
                       const float* __restrict__ h0,
                       const float* __restrict__ wih, const float* __restrict__ whh,
                       const float* __restrict__ w1,
                       float* __restrict__ A, float* __restrict__ Bm,
                       float* __restrict__ Ab, float* __restrict__ Bb,
                       float* __restrict__ hfirst, float* __restrict__ mask,
                       float* __restrict__ wihT, float* __restrict__ whhT,
                       float* __restrict__ w1T)
{
    int idx = blockIdx.x*256 + threadIdx.x;
    if (idx < 24576) {
        int r = idx >> 13;
        int c = (idx >> 6) & 127;
        int m = idx & 63;
        int t = 48 - 16*r;
        const float* src = w2 + c*4096 + m*64;
        float a = 0.f, b = 0.f;
        for (int k = 0; k < 64; k++){ float v = src[k]; if (k < t) a += v; else b += v; }
        A[idx] = a; Bm[idx] = b;
    } else if (idx < 24768) {
        int i2 = idx - 24576;
        int r = i2 >> 6, m = i2 & 63;
        int t = 48 - 16*r;
        const float* src = b2 + m*64;
        float a = 0.f, b = 0.f;
        for (int k = 0; k < 64; k++){ float v = src[k]; if (k < t) a += v; else b += v; }
        Ab[i2] = a; Bb[i2] = b;
    } else if (idx < 73920) {
        int i3 = idx - 24768;
        int node = i3 >> 6, m = i3 & 63;
        hfirst[i3] = (m < 32) ? h0[node*32 + m] : 0.f;
        if (m == 0) {
            float s = 0.f;
            for (int k = 0; k < 32; k++) s += h0[node*32 + k];
            mask[node] = (s > 0.f) ? 1.f : 0.f;
        }
    } else if (idx < 98496) {
        int i4 = idx - 73920;
        if (i4 < 12288) {
            int k = i4 / 192, col = i4 - k*192;
            wihT[i4] = wih[col*64 + k];
        } else {
            int i5 = i4 - 12288;
            int k = i5 / 192, col = i5 - k*192;
            whhT[i5] = whh[col*64 + k];
        }
    } else if (idx < 114880) {
        int i6 = idx - 98496;
        int o = i6 >> 7, i = i6 & 127;
        w1T[i6] = w1[i*128 + o];
    }
}

__global__ __launch_bounds__(256) void k_mlp(
    const float* __restrict__ ein, const float* __restrict__ w0, const float* __restrict__ b0,
    const float* __restrict__ w1T, const float* __restrict__ b1,
    float* __restrict__ relu2)
{
    __shared__ __align__(16) float x1s[64*132];
    int tid = threadIdx.x;
    int et = tid & 15, ot = tid >> 4;
    int o0 = ot * 8;
    size_t e0 = (size_t)blockIdx.x * 64;

    float acc[4][8];
    {
        float4 ba = *(const float4*)&b0[o0];
        float4 bb = *(const float4*)&b0[o0 + 4];
        #pragma unroll
        for (int q = 0; q < 4; q++){
            acc[q][0]=ba.x; acc[q][1]=ba.y; acc[q][2]=ba.z; acc[q][3]=ba.w;
            acc[q][4]=bb.x; acc[q][5]=bb.y; acc[q][6]=bb.z; acc[q][7]=bb.w;
        }
    }
    #pragma unroll
    for (int i4 = 0; i4 < 4; i4++){
        float4 ev[4];
        #pragma unroll
        for (int q = 0; q < 4; q++)
            ev[q] = *(const float4*)&ein[(e0 + q*16 + et)*16 + i4*4];
        #pragma unroll
        for (int d = 0; d < 4; d++){
            int i = i4*4 + d;
            float4 wa = *(const float4*)&w0[i*128 + o0];
            float4 wb = *(const float4*)&w0[i*128 + o0 + 4];
            #pragma unroll
            for (int q = 0; q < 4; q++){
                float xi = (d==0) ? ev[q].x : (d==1) ? ev[q].y : (d==2) ? ev[q].z : ev[q].w;
                acc[q][0] += xi*wa.x; acc[q][1] += xi*wa.y;
                acc[q][2] += xi*wa.z; acc[q][3] += xi*wa.w;
                acc[q][4] += xi*wb.x; acc[q][5] += xi*wb.y;
                acc[q][6] += xi*wb.z; acc[q][7] += xi*wb.w;
            }
        }
    }
    #pragma unroll
    for (int q = 0; q < 4; q++){
        int e = q*16 + et;
        float4 s0 = make_float4(fmaxf(acc[q][0],0.f), fmaxf(acc[q][1],0.f),
                                fmaxf(acc[q][2],0.f), fmaxf(acc[q][3],0.f));
        float4 s1 = make_float4(fmaxf(acc[q][4],0.f), fmaxf(acc[q][5],0.f),
                                fmaxf(acc[q][6],0.f), fmaxf(acc[q][7],0.f));
        *(float4*)&x1s[e*132 + o0]     = s0;
        *(float4*)&x1s[e*132 + o0 + 4] = s1;
    }
    __syncthreads();

    float a2[4][8];
    {
        float4 ba = *(const float4*)&b1[o0];
        float4 bb = *(const float4*)&b1[o0 + 4];
        #pragma unroll
        for (int q = 0; q < 4; q++){
            a2[q][0]=ba.x; a2[q][1]=ba.y; a2[q][2]=ba.z; a2[q][3]=ba.w;
            a2[q][4]=bb.x; a2[q][5]=bb.y; a2[q][6]=bb.z; a2[q][7]=bb.w;
        }
    }
    for (int i4 = 0; i4 < 32; i4++){
        int i = i4*4;
        float4 wv[8];
        #pragma unroll
        for (int r2 = 0; r2 < 8; r2++)
            wv[r2] = *(const float4*)&w1T[(size_t)(o0 + r2)*128 + i];
        #pragma unroll
        for (int q = 0; q < 4; q++){
            float4 xv = *(const float4*)&x1s[(q*16 + et)*132 + i];
            #pragma unroll
            for (int r2 = 0; r2 < 8; r2++){
                a2[q][r2] += xv.x*wv[r2].x + xv.y*wv[r2].y
                           + xv.z*wv[r2].z + xv.w*wv[r2].w;
            }
        }
    }
    #pragma unroll
    for (int q = 0; q < 4; q++){
        size_t e = e0 + q*16 + et;
        float4 s0 = make_float4(fmaxf(a2[q][0],0.f), fmaxf(a2[q][1],0.f),
                                fmaxf(a2[q][2],0.f), fmaxf(a2[q][3],0.f));
        float4 s1 = make_float4(fmaxf(a2[q][4],0.f), fmaxf(a2[q][5],0.f),
                                fmaxf(a2[q][6],0.f), fmaxf(a2[q][7],0.f));
        *(float4*)&relu2[e*128 + o0]     = s0;
        *(float4*)&relu2[e*128 + o0 + 4] = s1;
    }
}

__global__ __launch_bounds__(256) void k_layer(
    const float* __restrict__ hin, float* __restrict__ hout,
    const float* __restrict__ relu2,
    const float* __restrict__ A, const float* __restrict__ Bm,
    const float* __restrict__ Ab, const float* __restrict__ Bb,
    const float* __restrict__ g, const float* __restrict__ mask,
    const float* __restrict__ wihT, const float* __restrict__ whhT,
    const float* __restrict__ bih, const float* __restrict__ bhh)
{
    int bj = blockIdx.x;
    int b = bj / 48, j = bj - b*48;
    int r = j % 3;
    int p0 = j + j/3;
    int tid = threadIdx.x;
    int base = b*48;
    __shared__ float hs[64], wAs[48], wBs[48];
    __shared__ float pU[2][128], pV[2][128];
    __shared__ float Us[128], Vs[128];
    __shared__ float pC[4][64];
    __shared__ float sAB[2];
    __shared__ float aggs[64], gi[192], gh[192];

    if (tid < 64) hs[tid] = hin[(size_t)bj*64 + tid];
    else if (tid < 112){
        int i = tid - 64;
        int node = base + i;
        float gv = g[(size_t)node*48 + j];
        wAs[i] = gv * hin[(size_t)node*64 + p0];
        wBs[i] = gv * hin[(size_t)node*64 + p0 + 1];
    }
    __syncthreads();
    if (tid < 2){
        const float* src = tid ? wBs : wAs;
        float s = 0.f;
        for (int i = 0; i < 48; i++) s += src[i];
        sAB[tid] = s;
    }
    {
        int c = tid & 127, half = tid >> 7;
        const float* r2b = relu2 + ((size_t)base*48 + j)*128 + c;
        float aU = 0.f, aV = 0.f;
        for (int ii = 0; ii < 24; ii++){
            int i = half*24 + ii;
            float v = r2b[(size_t)i*6144];
            aU += wAs[i]*v; aV += wBs[i]*v;
        }
        pU[half][c] = aU; pV[half][c] = aV;
    }
    __syncthreads();
    if (tid < 128){ Us[tid] = pU[0][tid] + pU[1][tid]; Vs[tid] = pV[0][tid] + pV[1][tid]; }
    __syncthreads();
    {
        int m = tid & 63, cg = tid >> 6;
        const float* Arp = A  + r*8192 + m;
        const float* Brp = Bm + r*8192 + m;
        float a = 0.f;
        for (int cc = 0; cc < 32; cc++){
            int c = cg*32 + cc;
            a += Us[c]*Arp[c*64] + Vs[c]*Brp[c*64];
        }
        pC[cg][m] = a;
    }
    __syncthreads();
    if (tid < 64){
        aggs[tid] = pC[0][tid] + pC[1][tid] + pC[2][tid] + pC[3][tid]
                  + sAB[0]*Ab[r*64 + tid] + sAB[1]*Bb[r*64 + tid];
    }
    __syncthreads();
    if (tid < 192){
        float gacc = bih[tid], hacc = bhh[tid];
        for (int k = 0; k < 64; k++){
            gacc += aggs[k] * wihT[k*192 + tid];
            hacc += hs[k]   * whhT[k*192 + tid];
        }
        gi[tid] = gacc; gh[tid] = hacc;
    }
    __syncthreads();
    if (tid < 64){
        float rr = sigmoidf_(gi[tid] + gh[tid]);
        float zz = sigmoidf_(gi[64+tid] + gh[64+tid]);
        float nn = tanhf(gi[128+tid] + rr*gh[128+tid]);
        float hnew = (1.f - zz)*nn + zz*hs[tid];
        hout[(size_t)bj*64 + tid] = mask[bj] * hnew;
    }
}

__global__ __launch_bounds__(256) void k_read(
    const float* __restrict__ hfirst, const float* __restrict__ hT,
    const float* __restrict__ mask,
    const float* __restrict__ w00, const float* __restrict__ b00,
    const float* __restrict__ w01, const float* __restrict__ b01,
    const float* __restrict__ w02, const float* __restrict__ b02,
    const float* __restrict__ w10, const float* __restrict__ b10,
    const float* __restrict__ w11, const float* __restrict__ b11,
    const float* __restrict__ w12, const float* __restrict__ b12,
    float* __restrict__ partial)
{
    __shared__ __align__(16) float xs[4*128];
    __shared__ __align__(16) float ys[4*128];
    __shared__ __align__(16) float zs[4*128];
    __shared__ __align__(16) float os0[4*128];
    __shared__ float mS[4];
    int tid = threadIdx.x;
    int b = blockIdx.x / 12, gg = blockIdx.x - b*12;
    int node0 = b*48 + gg*4;
    int o = tid & 127, ng = tid >> 7;
    if (tid < 4) mS[tid] = mask[node0 + tid];
    for (int i = tid; i < 4*128; i += 256){
        int r = i >> 7, c = i & 127;
        xs[i] = (c < 64) ? hfirst[(size_t)(node0+r)*64 + c]
                         : hT[(size_t)(node0+r)*64 + (c - 64)];
    }
    __syncthreads();
    rd_layer_g(xs,      w00, b00, ys,  128, o, ng, true);  __syncthreads();
    rd_layer_g(ys,      w01, b01, zs,  128, o, ng, true);  __syncthreads();
    rd_layer_g(zs,      w02, b02, os0, 128, o, ng, false); __syncthreads();
    rd_layer_g(xs + 64, w10, b10, ys,  64,  o, ng, true);  __syncthreads();
    rd_layer_g(ys,      w11, b11, zs,  128, o, ng, true);  __syncthreads();
    {
        float a0 = b12[o];
        float a1 = a0;
        for (int i = 0; i < 128; i += 4){
            float w0 = w12[(size_t)(i+0)*128 + o];
            float w1 = w12[(size_t)(i+1)*128 + o];
            float w2 = w12[(size_t)(i+2)*128 + o];
            float w3 = w12[(size_t)(i+3)*128 + o];
            const float4 x0 = *(const float4*)&zs[ng*128 + i];
            const float4 x1 = *(const float4*)&zs[(ng+2)*128 + i];
            a0 += x0.x*w0 + x0.y*w1 + x0.z*w2 + x0.w*w3;
            a1 += x1.x*w0 + x1.y*w1 + x1.z*w2 + x1.w*w3;
        }
        float s = mS[ng]   * os0[ng*128 + o]     * a0
                + mS[ng+2] * os0[(ng+2)*128 + o] * a1;
        __syncthreads();
        ys[ng*128 + o] = s;
    }
    __syncthreads();
    if (tid < 128)
        partial[(size_t)blockIdx.x*128 + tid] = ys[tid] + ys[128 + tid];
}

__global__ void k_final(const float* __restrict__ partial, float* __restrict__ out)
{
    int idx = blockIdx.x*256 + threadIdx.x;
    if (idx < B_*128){
        int b = idx >> 7, t = idx & 127;
        float s = 0.f;
        for (int c = 0; c < 12; c++) s += partial[(size_t)(b*12 + c)*128 + t];
        out[idx] = 1.0f / (1.0f + expf(-s));
    }
}

// ---------------------------------------------------------------------------
extern "C" void kernel_launch(void* const* d_in, const int* in_sizes, int n_in,
                              void* d_out, int out_size, void* d_ws, size_t ws_size,
                              hipStream_t stream)
{
    (void)in_sizes; (void)n_in; (void)out_size; (void)ws_size;
    const float* g    = (const float*)d_in[0];
    const float* h0   = (const float*)d_in[1];
    const float* e    = (const float*)d_in[2];
    const float* mw0  = (const float*)d_in[3];
    const float* mb0  = (const float*)d_in[4];
    const float* mw1  = (const float*)d_in[5];
    const float* mb1  = (const float*)d_in[6];
    const float* mw2  = (const float*)d_in[7];
    const float* mb2  = (const float*)d_in[8];
    const float* wih  = (const float*)d_in[9];
    const float* whh  = (const float*)d_in[10];
    const float* bih  = (const float*)d_in[11];
    const float* bhh  = (const float*)d_in[12];
    const float* r0w0 = (const float*)d_in[13];
    const float* r0b0 = (const float*)d_in[14];
    const float* r0w1 = (const float*)d_in[15];
    const float* r0b1 = (const float*)d_in[16];
    const float* r0w2 = (const float*)d_in[17];
    const float* r0b2 = (const float*)d_in[18];
    const float* r1w0 = (const float*)d_in[19];
    const float* r1b0 = (const float*)d_in[20];
    const float* r1w1 = (const float*)d_in[21];
    const float* r1b1 = (const float*)d_in[22];
    const float* r1w2 = (const float*)d_in[23];
    const float* r1b2 = (const float*)d_in[24];
    float* out = (float*)d_out;

    float* ws     = (float*)d_ws;
    float* A      = ws;                  // 3*128*64   = 24576
    float* Bm     = A      + 24576;      //              24576
    float* Ab     = Bm     + 24576;      // 3*64       = 192
    float* Bb     = Ab     + 192;        //              192
    float* hfirst = Bb     + 192;        // 768*64     = 49152
    float* hA     = hfirst + 49152;
    float* hB     = hA     + 49152;
    float* mask   = hB     + 49152;      //              768
    float* wihT   = mask   + 768;        // 64*192     = 12288
    float* whhT   = wihT   + 12288;      //              12288
    float* w1T    = whhT   + 12288;      // 128*128    = 16384 (fallback only)
    float* part   = w1T    + 16384;      // 192*128    = 24576
    float* relu2  = part   + 24576;      // 36864*128  = 4718592

    KParams hp;
    hp.g = g; hp.h0 = h0; hp.e = e;
    hp.mw0 = mw0; hp.mb0 = mb0; hp.mw1 = mw1; hp.mb1 = mb1; hp.mw2 = mw2; hp.mb2 = mb2;
    hp.wih = wih; hp.whh = whh; hp.bih = bih; hp.bhh = bhh;
    hp.r0w0 = r0w0; hp.r0b0 = r0b0; hp.r0w1 = r0w1; hp.r0b1 = r0b1; hp.r0w2 = r0w2; hp.r0b2 = r0b2;
    hp.r1w0 = r1w0; hp.r1b0 = r1b0; hp.r1w1 = r1w1; hp.r1b1 = r1b1; hp.r1w2 = r1w2; hp.r1b2 = r1b2;
    hp.A = A; hp.Bm = Bm; hp.Ab = Ab; hp.Bb = Bb; hp.hfirst = hfirst; hp.hA = hA; hp.hB = hB;
    hp.mask = mask; hp.wihT = wihT; hp.whhT = whhT; hp.part = part; hp.relu2 = relu2; hp.out = out;

    void* args[] = { &hp };
    hipError_t err = hipLaunchCooperativeKernel((const void*)k_all, dim3(GRID_), dim3(256),
                                                args, 0, stream);
    if (err != hipSuccess) {
        // fallback: previous verified 7-kernel pipeline
        k_prep<<<449, 256, 0, stream>>>(mw2, mb2, h0, wih, whh, mw1,
                                        A, Bm, Ab, Bb, hfirst, mask, wihT, whhT, w1T);
        k_mlp<<<576, 256, 0, stream>>>(e, mw0, mb0, w1T, mb1, relu2);
        k_layer<<<768, 256, 0, stream>>>(hfirst, hA, relu2, A, Bm, Ab, Bb, g, mask,
                                         wihT, whhT, bih, bhh);
        k_layer<<<768, 256, 0, stream>>>(hA, hB, relu2, A, Bm, Ab, Bb, g, mask,
                                         wihT, whhT, bih, bhh);
        k_layer<<<768, 256, 0, stream>>>(hB, hA, relu2, A, Bm, Ab, Bb, g, mask,
                                         wihT, whhT, bih, bhh);
        k_read<<<192, 256, 0, stream>>>(hfirst, hA, mask,
                                        r0w0, r0b0, r0w1, r0b1, r0w2, r0b2,
                                        r1w0, r1b0, r1w1, r1b1, r1w2, r1b2, part);
        k_final<<<8, 256, 0, stream>>>(part, out);
    }
}

// Round 2
// 228.436 us; speedup vs baseline: 3.8090x; 3.8090x over previous
//
#include <hip/hip_runtime.h>
#include <cmath>

#define B_ 16
#define N_ 48

__device__ __forceinline__ float sigmoidf_(float x){ return 1.0f/(1.0f+expf(-x)); }

// ---------------------------------------------------------------------------
// k_prep: A/B column-sums of msg_w2 (3 variants by j%3), bias sums, hfirst,
// mask, transposed GRU weights (wihT/whhT [64][192]).  385 blocks x 256.
// ---------------------------------------------------------------------------
__global__ void k_prep(const float* __restrict__ w2, const float* __restrict__ b2,
                       const float* __restrict__ h0,
                       const float* __restrict__ wih, const float* __restrict__ whh,
                       float* __restrict__ A, float* __restrict__ Bm,
                       float* __restrict__ Ab, float* __restrict__ Bb,
                       float* __restrict__ hfirst, float* __restrict__ mask,
                       float* __restrict__ wihT, float* __restrict__ whhT)
{
    int idx = blockIdx.x*256 + threadIdx.x;
    if (idx < 24576) {
        int r = idx >> 13;          // 0..2
        int c = (idx >> 6) & 127;
        int m = idx & 63;
        int t = 48 - 16*r;
        const float* src = w2 + c*4096 + m*64;
        float a = 0.f, b = 0.f;
        for (int k = 0; k < 64; k++){ float v = src[k]; if (k < t) a += v; else b += v; }
        A[idx] = a; Bm[idx] = b;
    } else if (idx < 24768) {
        int i2 = idx - 24576;
        int r = i2 >> 6, m = i2 & 63;
        int t = 48 - 16*r;
        const float* src = b2 + m*64;
        float a = 0.f, b = 0.f;
        for (int k = 0; k < 64; k++){ float v = src[k]; if (k < t) a += v; else b += v; }
        Ab[i2] = a; Bb[i2] = b;
    } else if (idx < 73920) {
        int i3 = idx - 24768;
        int node = i3 >> 6, m = i3 & 63;
        hfirst[i3] = (m < 32) ? h0[node*32 + m] : 0.f;
        if (m == 0) {
            float s = 0.f;
            for (int k = 0; k < 32; k++) s += h0[node*32 + k];
            mask[node] = (s > 0.f) ? 1.f : 0.f;
        }
    } else if (idx < 98496) {
        int i4 = idx - 73920;
        if (i4 < 12288) {
            int k = i4 / 192, col = i4 - k*192;
            wihT[i4] = wih[col*64 + k];
        } else {
            int i5 = i4 - 12288;
            int k = i5 / 192, col = i5 - k*192;
            whhT[i5] = whh[col*64 + k];
        }
    }
}

// ---------------------------------------------------------------------------
// K1: edge MLP in COLUMN order (block = one (b,j) target) + fused layer 0.
// The block's 48-edge relu2 column stays in LDS and feeds L0 directly.
// Also writes relu2 to global for layers 1 and 2.
// ---------------------------------------------------------------------------
__global__ __launch_bounds__(256, 3) void k1_mlp_l0(
    const float* __restrict__ ein, const float* __restrict__ w0, const float* __restrict__ b0,
    const float* __restrict__ w1, const float* __restrict__ b1,
    const float* __restrict__ g, const float* __restrict__ h0,
    const float* __restrict__ mask,
    const float* __restrict__ A, const float* __restrict__ Bm,
    const float* __restrict__ Ab, const float* __restrict__ Bb,
    const float* __restrict__ wihT, const float* __restrict__ whhT,
    const float* __restrict__ bih, const float* __restrict__ bhh,
    float* __restrict__ relu2, float* __restrict__ hout)
{
    __shared__ __align__(16) float smem[12480];
    float* x1s = smem;           // [48][132] during MLP phase
    float* r2s = smem + 6336;    // [48][128], persists into L0
    const int tid  = threadIdx.x;
    const int bj   = blockIdx.x;
    const int b    = bj / 48, j = bj - b*48;
    const int base = b*48;

    // ---- MLP layer 1 ----
    const int et = tid & 15;
    const int o0 = (tid >> 4) * 8;
    size_t eg[3];
    #pragma unroll
    for (int q = 0; q < 3; q++)
        eg[q] = ((size_t)(base + q*16 + et)*48 + j);

    float acc[3][8];
    {
        float4 ba = *(const float4*)&b0[o0];
        float4 bb = *(const float4*)&b0[o0 + 4];
        #pragma unroll
        for (int q = 0; q < 3; q++){
            acc[q][0]=ba.x; acc[q][1]=ba.y; acc[q][2]=ba.z; acc[q][3]=ba.w;
            acc[q][4]=bb.x; acc[q][5]=bb.y; acc[q][6]=bb.z; acc[q][7]=bb.w;
        }
    }
    #pragma unroll
    for (int i4 = 0; i4 < 4; i4++){
        float4 ev[3];
        #pragma unroll
        for (int q = 0; q < 3; q++)
            ev[q] = *(const float4*)&ein[eg[q]*16 + i4*4];
        #pragma unroll
        for (int d = 0; d < 4; d++){
            int i = i4*4 + d;
            float4 wa = *(const float4*)&w0[i*128 + o0];
            float4 wb = *(const float4*)&w0[i*128 + o0 + 4];
            #pragma unroll
            for (int q = 0; q < 3; q++){
                float xi = (d==0) ? ev[q].x : (d==1) ? ev[q].y : (d==2) ? ev[q].z : ev[q].w;
                acc[q][0] += xi*wa.x; acc[q][1] += xi*wa.y;
                acc[q][2] += xi*wa.z; acc[q][3] += xi*wa.w;
                acc[q][4] += xi*wb.x; acc[q][5] += xi*wb.y;
                acc[q][6] += xi*wb.z; acc[q][7] += xi*wb.w;
            }
        }
    }
    #pragma unroll
    for (int q = 0; q < 3; q++){
        int el = q*16 + et;
        *(float4*)&x1s[el*132 + o0] =
            make_float4(fmaxf(acc[q][0],0.f), fmaxf(acc[q][1],0.f),
                        fmaxf(acc[q][2],0.f), fmaxf(acc[q][3],0.f));
        *(float4*)&x1s[el*132 + o0 + 4] =
            make_float4(fmaxf(acc[q][4],0.f), fmaxf(acc[q][5],0.f),
                        fmaxf(acc[q][6],0.f), fmaxf(acc[q][7],0.f));
    }
    __syncthreads();

    // ---- MLP layer 2 (reads mw1 rows directly) ----
    float a2[3][8];
    {
        float4 ba = *(const float4*)&b1[o0];
        float4 bb = *(const float4*)&b1[o0 + 4];
        #pragma unroll
        for (int q = 0; q < 3; q++){
            a2[q][0]=ba.x; a2[q][1]=ba.y; a2[q][2]=ba.z; a2[q][3]=ba.w;
            a2[q][4]=bb.x; a2[q][5]=bb.y; a2[q][6]=bb.z; a2[q][7]=bb.w;
        }
    }
    for (int i4 = 0; i4 < 32; i4++){
        int i = i4*4;
        float4 w0a = *(const float4*)&w1[(size_t)(i+0)*128 + o0];
        float4 w0b = *(const float4*)&w1[(size_t)(i+0)*128 + o0 + 4];
        float4 w1a = *(const float4*)&w1[(size_t)(i+1)*128 + o0];
        float4 w1b = *(const float4*)&w1[(size_t)(i+1)*128 + o0 + 4];
        float4 w2a = *(const float4*)&w1[(size_t)(i+2)*128 + o0];
        float4 w2b = *(const float4*)&w1[(size_t)(i+2)*128 + o0 + 4];
        float4 w3a = *(const float4*)&w1[(size_t)(i+3)*128 + o0];
        float4 w3b = *(const float4*)&w1[(size_t)(i+3)*128 + o0 + 4];
        float4 xv[3];
        #pragma unroll
        for (int q = 0; q < 3; q++)
            xv[q] = *(const float4*)&x1s[(q*16 + et)*132 + i];
        #pragma unroll
        for (int q = 0; q < 3; q++){
            float4 x = xv[q];
            a2[q][0] += x.x*w0a.x + x.y*w1a.x + x.z*w2a.x + x.w*w3a.x;
            a2[q][1] += x.x*w0a.y + x.y*w1a.y + x.z*w2a.y + x.w*w3a.y;
            a2[q][2] += x.x*w0a.z + x.y*w1a.z + x.z*w2a.z + x.w*w3a.z;
            a2[q][3] += x.x*w0a.w + x.y*w1a.w + x.z*w2a.w + x.w*w3a.w;
            a2[q][4] += x.x*w0b.x + x.y*w1b.x + x.z*w2b.x + x.w*w3b.x;
            a2[q][5] += x.x*w0b.y + x.y*w1b.y + x.z*w2b.y + x.w*w3b.y;
            a2[q][6] += x.x*w0b.z + x.y*w1b.z + x.z*w2b.z + x.w*w3b.z;
            a2[q][7] += x.x*w0b.w + x.y*w1b.w + x.z*w2b.w + x.w*w3b.w;
        }
    }
    #pragma unroll
    for (int q = 0; q < 3; q++){
        int el = q*16 + et;
        float4 s0 = make_float4(fmaxf(a2[q][0],0.f), fmaxf(a2[q][1],0.f),
                                fmaxf(a2[q][2],0.f), fmaxf(a2[q][3],0.f));
        float4 s1 = make_float4(fmaxf(a2[q][4],0.f), fmaxf(a2[q][5],0.f),
                                fmaxf(a2[q][6],0.f), fmaxf(a2[q][7],0.f));
        *(float4*)&r2s[el*128 + o0]     = s0;
        *(float4*)&r2s[el*128 + o0 + 4] = s1;
        *(float4*)&relu2[eg[q]*128 + o0]     = s0;
        *(float4*)&relu2[eg[q]*128 + o0 + 4] = s1;
    }
    __syncthreads();

    // ---- layer 0 (relu2 column from LDS; hfirst synthesized from h0) ----
    float* hs   = smem;        // 64
    float* wAs  = smem + 64;   // 48
    float* wBs  = smem + 112;  // 48
    float* sAB  = smem + 160;  // 2
    float* pU   = smem + 162;  // 2*128
    float* pV   = smem + 418;  // 2*128
    float* Us   = smem + 674;  // 128
    float* Vs   = smem + 802;  // 128
    float* pC   = smem + 930;  // 4*64
    float* aggs = smem + 1186; // 64
    float* gi   = smem + 1250; // 192
    float* gh   = smem + 1442; // 192 (ends 1634 < 6336, r2s untouched)

    const int r  = j % 3;
    const int q0 = j + j/3;

    if (tid < 64) hs[tid] = (tid < 32) ? h0[bj*32 + tid] : 0.f;
    else if (tid < 112){
        int i = tid - 64;
        int node = base + i;
        float gv = g[(size_t)node*48 + j];
        float ha = (q0   < 32) ? h0[node*32 + q0]     : 0.f;
        float hb = (q0+1 < 32) ? h0[node*32 + q0 + 1] : 0.f;
        wAs[i] = gv * ha;
        wBs[i] = gv * hb;
    }
    __syncthreads();
    if (tid < 2){
        const float* src = tid ? wBs : wAs;
        float s = 0.f;
        for (int i = 0; i < 48; i++) s += src[i];
        sAB[tid] = s;
    }
    {   // U/V partials (same 2x24 order as verified kernel)
        int c = tid & 127, half = tid >> 7;
        const float* rb = r2s + c;
        float aU = 0.f, aV = 0.f;
        for (int ii = 0; ii < 24; ii++){
            int i = half*24 + ii;
            float v = rb[i*128];
            aU += wAs[i]*v; aV += wBs[i]*v;
        }
        pU[half*128 + c] = aU; pV[half*128 + c] = aV;
    }
    __syncthreads();
    if (tid < 128){ Us[tid] = pU[tid] + pU[128 + tid]; }
    else { int c = tid - 128; Vs[c] = pV[c] + pV[128 + c]; }
    __syncthreads();
    {   // agg = U@A_r + V@B_r
        int m = tid & 63, cg2 = tid >> 6;
        const float* Arp = A  + r*8192 + m;
        const float* Brp = Bm + r*8192 + m;
        float a = 0.f;
        for (int cc = 0; cc < 32; cc++){
            int c = cg2*32 + cc;
            a += Us[c]*Arp[c*64] + Vs[c]*Brp[c*64];
        }
        pC[cg2*64 + m] = a;
    }
    __syncthreads();
    if (tid < 64){
        aggs[tid] = pC[tid] + pC[64+tid] + pC[128+tid] + pC[192+tid]
                  + sAB[0]*Ab[r*64 + tid] + sAB[1]*Bb[r*64 + tid];
    }
    __syncthreads();
    if (tid < 192){
        float gacc = bih[tid], hacc = bhh[tid];
        for (int k = 0; k < 64; k++){
            gacc += aggs[k] * wihT[k*192 + tid];
            hacc += hs[k]   * whhT[k*192 + tid];
        }
        gi[tid] = gacc; gh[tid] = hacc;
    }
    __syncthreads();
    if (tid < 64){
        float rr = sigmoidf_(gi[tid] + gh[tid]);
        float zz = sigmoidf_(gi[64+tid] + gh[64+tid]);
        float nn = tanhf(gi[128+tid] + rr*gh[128+tid]);
        float hnew = (1.f - zz)*nn + zz*hs[tid];
        hout[(size_t)bj*64 + tid] = mask[bj] * hnew;
    }
}

// ---------------------------------------------------------------------------
// K2: middle message-passing layer (verified structure, unchanged)
// ---------------------------------------------------------------------------
__global__ __launch_bounds__(256) void k_layer(
    const float* __restrict__ hin, float* __restrict__ hout,
    const float* __restrict__ relu2,
    const float* __restrict__ A, const float* __restrict__ Bm,
    const float* __restrict__ Ab, const float* __restrict__ Bb,
    const float* __restrict__ g, const float* __restrict__ mask,
    const float* __restrict__ wihT, const float* __restrict__ whhT,
    const float* __restrict__ bih, const float* __restrict__ bhh)
{
    int bj = blockIdx.x;
    int b = bj / 48, j = bj - b*48;
    int r = j % 3;
    int p0 = j + j/3;
    int tid = threadIdx.x;
    int base = b*48;
    __shared__ float hs[64], wAs[48], wBs[48];
    __shared__ float pU[2][128], pV[2][128];
    __shared__ float Us[128], Vs[128];
    __shared__ float pC[4][64];
    __shared__ float sAB[2];
    __shared__ float aggs[64], gi[192], gh[192];

    if (tid < 64) hs[tid] = hin[(size_t)bj*64 + tid];
    else if (tid < 112){
        int i = tid - 64;
        int node = base + i;
        float gv = g[(size_t)node*48 + j];
        wAs[i] = gv * hin[(size_t)node*64 + p0];
        wBs[i] = gv * hin[(size_t)node*64 + p0 + 1];
    }
    __syncthreads();
    if (tid < 2){
        const float* src = tid ? wBs : wAs;
        float s = 0.f;
        for (int i = 0; i < 48; i++) s += src[i];
        sAB[tid] = s;
    }
    {
        int c = tid & 127, half = tid >> 7;
        const float* r2b = relu2 + ((size_t)base*48 + j)*128 + c;
        float aU = 0.f, aV = 0.f;
        for (int ii = 0; ii < 24; ii++){
            int i = half*24 + ii;
            float v = r2b[(size_t)i*6144];
            aU += wAs[i]*v; aV += wBs[i]*v;
        }
        pU[half][c] = aU; pV[half][c] = aV;
    }
    __syncthreads();
    if (tid < 128){ Us[tid] = pU[0][tid] + pU[1][tid]; Vs[tid] = pV[0][tid] + pV[1][tid]; }
    __syncthreads();
    {
        int m = tid & 63, cg = tid >> 6;
        const float* Arp = A  + r*8192 + m;
        const float* Brp = Bm + r*8192 + m;
        float a = 0.f;
        for (int cc = 0; cc < 32; cc++){
            int c = cg*32 + cc;
            a += Us[c]*Arp[c*64] + Vs[c]*Brp[c*64];
        }
        pC[cg][m] = a;
    }
    __syncthreads();
    if (tid < 64){
        aggs[tid] = pC[0][tid] + pC[1][tid] + pC[2][tid] + pC[3][tid]
                  + sAB[0]*Ab[r*64 + tid] + sAB[1]*Bb[r*64 + tid];
    }
    __syncthreads();
    if (tid < 192){
        float gacc = bih[tid], hacc = bhh[tid];
        for (int k = 0; k < 64; k++){
            gacc += aggs[k] * wihT[k*192 + tid];
            hacc += hs[k]   * whhT[k*192 + tid];
        }
        gi[tid] = gacc; gh[tid] = hacc;
    }
    __syncthreads();
    if (tid < 64){
        float rr = sigmoidf_(gi[tid] + gh[tid]);
        float zz = sigmoidf_(gi[64+tid] + gh[64+tid]);
        float nn = tanhf(gi[128+tid] + rr*gh[128+tid]);
        float hnew = (1.f - zz)*nn + zz*hs[tid];
        hout[(size_t)bj*64 + tid] = mask[bj] * hnew;
    }
}

// ---------------------------------------------------------------------------
// K3: last message-passing layer + fused per-node readout.
// h_T never leaves LDS; block writes part[node][128] = mask*Net0*Net1.
// ---------------------------------------------------------------------------
__global__ __launch_bounds__(256) void k3_layer_read(
    const float* __restrict__ hin,
    const float* __restrict__ relu2,
    const float* __restrict__ A, const float* __restrict__ Bm,
    const float* __restrict__ Ab, const float* __restrict__ Bb,
    const float* __restrict__ g, const float* __restrict__ mask,
    const float* __restrict__ wihT, const float* __restrict__ whhT,
    const float* __restrict__ bih, const float* __restrict__ bhh,
    const float* __restrict__ hfirst,
    const float* __restrict__ w00, const float* __restrict__ b00,
    const float* __restrict__ w01, const float* __restrict__ b01,
    const float* __restrict__ w02, const float* __restrict__ b02,
    const float* __restrict__ w10, const float* __restrict__ b10,
    const float* __restrict__ w11, const float* __restrict__ b11,
    const float* __restrict__ w12, const float* __restrict__ b12,
    float* __restrict__ part)
{
    int bj = blockIdx.x;
    int b = bj / 48, j = bj - b*48;
    int r = j % 3;
    int p0 = j + j/3;
    int tid = threadIdx.x;
    int base = b*48;
    __shared__ float hs[64], wAs[48], wBs[48];
    __shared__ float pU[2][128], pV[2][128];
    __shared__ float Us[128], Vs[128];
    __shared__ float pC[4][64];
    __shared__ float sAB[2];
    __shared__ float aggs[64], gi[192], gh[192];
    __shared__ float hfs[64], hTs[64];
    __shared__ float ps[256], bufA[128], bufB[128], os0[128];

    if (tid < 64) hs[tid] = hin[(size_t)bj*64 + tid];
    else if (tid < 112){
        int i = tid - 64;
        int node = base + i;
        float gv = g[(size_t)node*48 + j];
        wAs[i] = gv * hin[(size_t)node*64 + p0];
        wBs[i] = gv * hin[(size_t)node*64 + p0 + 1];
    }
    else if (tid < 176){
        hfs[tid - 112] = hfirst[(size_t)bj*64 + (tid - 112)];
    }
    __syncthreads();
    if (tid < 2){
        const float* src = tid ? wBs : wAs;
        float s = 0.f;
        for (int i = 0; i < 48; i++) s += src[i];
        sAB[tid] = s;
    }
    {
        int c = tid & 127, half = tid >> 7;
        const float* r2b = relu2 + ((size_t)base*48 + j)*128 + c;
        float aU = 0.f, aV = 0.f;
        for (int ii = 0; ii < 24; ii++){
            int i = half*24 + ii;
            float v = r2b[(size_t)i*6144];
            aU += wAs[i]*v; aV += wBs[i]*v;
        }
        pU[half][c] = aU; pV[half][c] = aV;
    }
    __syncthreads();
    if (tid < 128){ Us[tid] = pU[0][tid] + pU[1][tid]; Vs[tid] = pV[0][tid] + pV[1][tid]; }
    __syncthreads();
    {
        int m = tid & 63, cg = tid >> 6;
        const float* Arp = A  + r*8192 + m;
        const float* Brp = Bm + r*8192 + m;
        float a = 0.f;
        for (int cc = 0; cc < 32; cc++){
            int c = cg*32 + cc;
            a += Us[c]*Arp[c*64] + Vs[c]*Brp[c*64];
        }
        pC[cg][m] = a;
    }
    __syncthreads();
    if (tid < 64){
        aggs[tid] = pC[0][tid] + pC[1][tid] + pC[2][tid] + pC[3][tid]
                  + sAB[0]*Ab[r*64 + tid] + sAB[1]*Bb[r*64 + tid];
    }
    __syncthreads();
    if (tid < 192){
        float gacc = bih[tid], hacc = bhh[tid];
        for (int k = 0; k < 64; k++){
            gacc += aggs[k] * wihT[k*192 + tid];
            hacc += hs[k]   * whhT[k*192 + tid];
        }
        gi[tid] = gacc; gh[tid] = hacc;
    }
    __syncthreads();
    if (tid < 64){
        float rr = sigmoidf_(gi[tid] + gh[tid]);
        float zz = sigmoidf_(gi[64+tid] + gh[64+tid]);
        float nn = tanhf(gi[128+tid] + rr*gh[128+tid]);
        float hnew = (1.f - zz)*nn + zz*hs[tid];
        hTs[tid] = mask[bj] * hnew;       // h_T stays in LDS
    }
    __syncthreads();

    // ---- fused readout for node bj ----
    int o = tid & 127, hh = tid >> 7;
    // Net0 layer 0: X = [hfs | hTs]
    {
        float a = 0.f;
        for (int i = hh*64; i < hh*64 + 64; i++){
            float x = (i < 64) ? hfs[i] : hTs[i - 64];
            a += x * w00[(size_t)i*128 + o];
        }
        ps[hh*128 + o] = a;
    }
    __syncthreads();
    if (tid < 128) bufA[o] = fmaxf(b00[o] + ps[o] + ps[128 + o], 0.f);
    __syncthreads();
    // Net0 layer 1
    {
        float a = 0.f;
        for (int i = hh*64; i < hh*64 + 64; i++)
            a += bufA[i] * w01[(size_t)i*128 + o];
        ps[hh*128 + o] = a;
    }
    __syncthreads();
    if (tid < 128) bufB[o] = fmaxf(b01[o] + ps[o] + ps[128 + o], 0.f);
    __syncthreads();
    // Net0 layer 2 (linear)
    {
        float a = 0.f;
        for (int i = hh*64; i < hh*64 + 64; i++)
            a += bufB[i] * w02[(size_t)i*128 + o];
        ps[hh*128 + o] = a;
    }
    __syncthreads();
    if (tid < 128) os0[o] = b02[o] + ps[o] + ps[128 + o];
    __syncthreads();
    // Net1 layer 0: input hTs (64)
    {
        float a = 0.f;
        for (int i = hh*32; i < hh*32 + 32; i++)
            a += hTs[i] * w10[(size_t)i*128 + o];
        ps[hh*128 + o] = a;
    }
    __syncthreads();
    if (tid < 128) bufA[o] = fmaxf(b10[o] + ps[o] + ps[128 + o], 0.f);
    __syncthreads();
    // Net1 layer 1
    {
        float a = 0.f;
        for (int i = hh*64; i < hh*64 + 64; i++)
            a += bufA[i] * w11[(size_t)i*128 + o];
        ps[hh*128 + o] = a;
    }
    __syncthreads();
    if (tid < 128) bufB[o] = fmaxf(b11[o] + ps[o] + ps[128 + o], 0.f);
    __syncthreads();
    // Net1 layer 2 (linear) + combine
    {
        float a = 0.f;
        for (int i = hh*64; i < hh*64 + 64; i++)
            a += bufB[i] * w12[(size_t)i*128 + o];
        ps[hh*128 + o] = a;
    }
    __syncthreads();
    if (tid < 128){
        float r1o = b12[o] + ps[o] + ps[128 + o];
        part[(size_t)bj*128 + o] = mask[bj] * os0[o] * r1o;
    }
}

// ---------------------------------------------------------------------------
// k_final: sum 48 node partials per batch + sigmoid
// ---------------------------------------------------------------------------
__global__ void k_final(const float* __restrict__ part, float* __restrict__ out)
{
    int idx = blockIdx.x*256 + threadIdx.x;
    if (idx < B_*128){
        int b = idx >> 7, t = idx & 127;
        float s = 0.f;
        for (int n = 0; n < 48; n++) s += part[(size_t)(b*48 + n)*128 + t];
        out[idx] = 1.0f / (1.0f + expf(-s));
    }
}

// ---------------------------------------------------------------------------
extern "C" void kernel_launch(void* const* d_in, const int* in_sizes, int n_in,
                              void* d_out, int out_size, void* d_ws, size_t ws_size,
                              hipStream_t stream)
{
    (void)in_sizes; (void)n_in; (void)out_size; (void)ws_size;
    const float* g    = (const float*)d_in[0];
    const float* h0   = (const float*)d_in[1];
    const float* e    = (const float*)d_in[2];
    const float* mw0  = (const float*)d_in[3];
    const float* mb0  = (const float*)d_in[4];
    const float* mw1  = (const float*)d_in[5];
    const float* mb1  = (const float*)d_in[6];
    const float* mw2  = (const float*)d_in[7];
    const float* mb2  = (const float*)d_in[8];
    const float* wih  = (const float*)d_in[9];
    const float* whh  = (const float*)d_in[10];
    const float* bih  = (const float*)d_in[11];
    const float* bhh  = (const float*)d_in[12];
    const float* r0w0 = (const float*)d_in[13];
    const float* r0b0 = (const float*)d_in[14];
    const float* r0w1 = (const float*)d_in[15];
    const float* r0b1 = (const float*)d_in[16];
    const float* r0w2 = (const float*)d_in[17];
    const float* r0b2 = (const float*)d_in[18];
    const float* r1w0 = (const float*)d_in[19];
    const float* r1b0 = (const float*)d_in[20];
    const float* r1w1 = (const float*)d_in[21];
    const float* r1b1 = (const float*)d_in[22];
    const float* r1w2 = (const float*)d_in[23];
    const float* r1b2 = (const float*)d_in[24];
    float* out = (float*)d_out;

    float* ws     = (float*)d_ws;
    float* A      = ws;                  // 3*128*64   = 24576
    float* Bm     = A      + 24576;      //              24576
    float* Ab     = Bm     + 24576;      // 3*64       = 192
    float* Bb     = Ab     + 192;        //              192
    float* hfirst = Bb     + 192;        // 768*64     = 49152
    float* hA     = hfirst + 49152;      //              49152
    float* hB     = hA     + 49152;      //              49152
    float* mask   = hB     + 49152;      //              768
    float* wihT   = mask   + 768;        // 64*192     = 12288
    float* whhT   = wihT   + 12288;      //              12288
    float* part   = whhT   + 12288;      // 768*128    = 98304
    float* relu2  = part   + 98304;      // 36864*128  = 4718592
    // total ~ 5.06M floats = 19.3 MiB

    k_prep<<<385, 256, 0, stream>>>(mw2, mb2, h0, wih, whh,
                                    A, Bm, Ab, Bb, hfirst, mask, wihT, whhT);
    k1_mlp_l0<<<768, 256, 0, stream>>>(e, mw0, mb0, mw1, mb1, g, h0, mask,
                                       A, Bm, Ab, Bb, wihT, whhT, bih, bhh,
                                       relu2, hA);
    k_layer<<<768, 256, 0, stream>>>(hA, hB, relu2, A, Bm, Ab, Bb, g, mask,
                                     wihT, whhT, bih, bhh);
    k3_layer_read<<<768, 256, 0, stream>>>(hB, relu2, A, Bm, Ab, Bb, g, mask,
                                           wihT, whhT, bih, bhh, hfirst,
                                           r0w0, r0b0, r0w1, r0b1, r0w2, r0b2,
                                           r1w0, r1b0, r1w1, r1b1, r1w2, r1b2,
                                           part);
    k_final<<<8, 256, 0, stream>>>(part, out);
}

// Round 3
// 196.169 us; speedup vs baseline: 4.4356x; 1.1645x over previous
//
#include <hip/hip_runtime.h>
#include <cmath>

#define B_ 16
#define N_ 48

__device__ __forceinline__ float sigmoidf_(float x){ return 1.0f/(1.0f+expf(-x)); }

// ---------------------------------------------------------------------------
// k_prep: A/B column-sums of msg_w2, bias sums, hfirst, mask, transposed GRU
// weights, and eT[b][j][i][16] transpose of e.  961 blocks x 256.
// ---------------------------------------------------------------------------
__global__ void k_prep(const float* __restrict__ w2, const float* __restrict__ b2,
                       const float* __restrict__ h0,
                       const float* __restrict__ wih, const float* __restrict__ whh,
                       const float* __restrict__ e,
                       float* __restrict__ A, float* __restrict__ Bm,
                       float* __restrict__ Ab, float* __restrict__ Bb,
                       float* __restrict__ hfirst, float* __restrict__ mask,
                       float* __restrict__ wihT, float* __restrict__ whhT,
                       float* __restrict__ eT)
{
    int idx = blockIdx.x*256 + threadIdx.x;
    if (idx < 24576) {
        int r = idx >> 13;          // 0..2
        int c = (idx >> 6) & 127;
        int m = idx & 63;
        int t = 48 - 16*r;
        const float* src = w2 + c*4096 + m*64;
        float a = 0.f, b = 0.f;
        for (int k = 0; k < 64; k++){ float v = src[k]; if (k < t) a += v; else b += v; }
        A[idx] = a; Bm[idx] = b;
    } else if (idx < 24768) {
        int i2 = idx - 24576;
        int r = i2 >> 6, m = i2 & 63;
        int t = 48 - 16*r;
        const float* src = b2 + m*64;
        float a = 0.f, b = 0.f;
        for (int k = 0; k < 64; k++){ float v = src[k]; if (k < t) a += v; else b += v; }
        Ab[i2] = a; Bb[i2] = b;
    } else if (idx < 73920) {
        int i3 = idx - 24768;
        int node = i3 >> 6, m = i3 & 63;
        hfirst[i3] = (m < 32) ? h0[node*32 + m] : 0.f;
        if (m == 0) {
            float s = 0.f;
            for (int k = 0; k < 32; k++) s += h0[node*32 + k];
            mask[node] = (s > 0.f) ? 1.f : 0.f;
        }
    } else if (idx < 98496) {
        int i4 = idx - 73920;
        if (i4 < 12288) {
            int k = i4 / 192, col = i4 - k*192;
            wihT[i4] = wih[col*64 + k];
        } else {
            int i5 = i4 - 12288;
            int k = i5 / 192, col = i5 - k*192;
            whhT[i5] = whh[col*64 + k];
        }
    } else if (idx < 245952) {
        // eT transpose: read e coalesced (float4), write scattered 16B
        int i6 = idx - 98496;            // float4 index over e, [0, 147456)
        int d4 = i6 & 3;
        int E  = i6 >> 2;                // (b*48 + i)*48 + j
        int j  = E % 48;
        int bi = E / 48;
        int i  = bi % 48;
        int b  = bi / 48;
        float4 v = *(const float4*)&e[(size_t)i6*4];
        *(float4*)&eT[(((size_t)(b*48 + j)*48 + i)*4 + d4)*4] = v;
    }
}

// ---------------------------------------------------------------------------
// K1: edge MLP in COLUMN order (block = one (b,j) target) + fused layer 0.
// Reads eT (block-contiguous), writes relu2T (block-contiguous 24 KB).
// ---------------------------------------------------------------------------
__global__ __launch_bounds__(256, 3) void k1_mlp_l0(
    const float* __restrict__ eT, const float* __restrict__ w0, const float* __restrict__ b0,
    const float* __restrict__ w1, const float* __restrict__ b1,
    const float* __restrict__ g, const float* __restrict__ h0,
    const float* __restrict__ mask,
    const float* __restrict__ A, const float* __restrict__ Bm,
    const float* __restrict__ Ab, const float* __restrict__ Bb,
    const float* __restrict__ wihT, const float* __restrict__ whhT,
    const float* __restrict__ bih, const float* __restrict__ bhh,
    float* __restrict__ relu2T, float* __restrict__ hout)
{
    __shared__ __align__(16) float smem[12480];
    float* x1s = smem;           // [48][132] during MLP phase
    float* r2s = smem + 6336;    // [48][128], persists into L0
    const int tid  = threadIdx.x;
    const int bj   = blockIdx.x;
    const int b    = bj / 48, j = bj - b*48;
    const int base = b*48;

    // ---- MLP layer 1 ----
    const int et = tid & 15;
    const int o0 = (tid >> 4) * 8;
    const size_t ebase = (size_t)bj * 48;   // block's 48 edges, contiguous

    float acc[3][8];
    {
        float4 ba = *(const float4*)&b0[o0];
        float4 bb = *(const float4*)&b0[o0 + 4];
        #pragma unroll
        for (int q = 0; q < 3; q++){
            acc[q][0]=ba.x; acc[q][1]=ba.y; acc[q][2]=ba.z; acc[q][3]=ba.w;
            acc[q][4]=bb.x; acc[q][5]=bb.y; acc[q][6]=bb.z; acc[q][7]=bb.w;
        }
    }
    #pragma unroll
    for (int i4 = 0; i4 < 4; i4++){
        float4 ev[3];
        #pragma unroll
        for (int q = 0; q < 3; q++)
            ev[q] = *(const float4*)&eT[(ebase + q*16 + et)*16 + i4*4];
        #pragma unroll
        for (int d = 0; d < 4; d++){
            int i = i4*4 + d;
            float4 wa = *(const float4*)&w0[i*128 + o0];
            float4 wb = *(const float4*)&w0[i*128 + o0 + 4];
            #pragma unroll
            for (int q = 0; q < 3; q++){
                float xi = (d==0) ? ev[q].x : (d==1) ? ev[q].y : (d==2) ? ev[q].z : ev[q].w;
                acc[q][0] += xi*wa.x; acc[q][1] += xi*wa.y;
                acc[q][2] += xi*wa.z; acc[q][3] += xi*wa.w;
                acc[q][4] += xi*wb.x; acc[q][5] += xi*wb.y;
                acc[q][6] += xi*wb.z; acc[q][7] += xi*wb.w;
            }
        }
    }
    #pragma unroll
    for (int q = 0; q < 3; q++){
        int el = q*16 + et;
        *(float4*)&x1s[el*132 + o0] =
            make_float4(fmaxf(acc[q][0],0.f), fmaxf(acc[q][1],0.f),
                        fmaxf(acc[q][2],0.f), fmaxf(acc[q][3],0.f));
        *(float4*)&x1s[el*132 + o0 + 4] =
            make_float4(fmaxf(acc[q][4],0.f), fmaxf(acc[q][5],0.f),
                        fmaxf(acc[q][6],0.f), fmaxf(acc[q][7],0.f));
    }
    __syncthreads();

    // ---- MLP layer 2 (reads mw1 rows directly) ----
    float a2[3][8];
    {
        float4 ba = *(const float4*)&b1[o0];
        float4 bb = *(const float4*)&b1[o0 + 4];
        #pragma unroll
        for (int q = 0; q < 3; q++){
            a2[q][0]=ba.x; a2[q][1]=ba.y; a2[q][2]=ba.z; a2[q][3]=ba.w;
            a2[q][4]=bb.x; a2[q][5]=bb.y; a2[q][6]=bb.z; a2[q][7]=bb.w;
        }
    }
    for (int i4 = 0; i4 < 32; i4++){
        int i = i4*4;
        float4 w0a = *(const float4*)&w1[(size_t)(i+0)*128 + o0];
        float4 w0b = *(const float4*)&w1[(size_t)(i+0)*128 + o0 + 4];
        float4 w1a = *(const float4*)&w1[(size_t)(i+1)*128 + o0];
        float4 w1b = *(const float4*)&w1[(size_t)(i+1)*128 + o0 + 4];
        float4 w2a = *(const float4*)&w1[(size_t)(i+2)*128 + o0];
        float4 w2b = *(const float4*)&w1[(size_t)(i+2)*128 + o0 + 4];
        float4 w3a = *(const float4*)&w1[(size_t)(i+3)*128 + o0];
        float4 w3b = *(const float4*)&w1[(size_t)(i+3)*128 + o0 + 4];
        float4 xv[3];
        #pragma unroll
        for (int q = 0; q < 3; q++)
            xv[q] = *(const float4*)&x1s[(q*16 + et)*132 + i];
        #pragma unroll
        for (int q = 0; q < 3; q++){
            float4 x = xv[q];
            a2[q][0] += x.x*w0a.x + x.y*w1a.x + x.z*w2a.x + x.w*w3a.x;
            a2[q][1] += x.x*w0a.y + x.y*w1a.y + x.z*w2a.y + x.w*w3a.y;
            a2[q][2] += x.x*w0a.z + x.y*w1a.z + x.z*w2a.z + x.w*w3a.z;
            a2[q][3] += x.x*w0a.w + x.y*w1a.w + x.z*w2a.w + x.w*w3a.w;
            a2[q][4] += x.x*w0b.x + x.y*w1b.x + x.z*w2b.x + x.w*w3b.x;
            a2[q][5] += x.x*w0b.y + x.y*w1b.y + x.z*w2b.y + x.w*w3b.y;
            a2[q][6] += x.x*w0b.z + x.y*w1b.z + x.z*w2b.z + x.w*w3b.z;
            a2[q][7] += x.x*w0b.w + x.y*w1b.w + x.z*w2b.w + x.w*w3b.w;
        }
    }
    #pragma unroll
    for (int q = 0; q < 3; q++){
        int el = q*16 + et;
        float4 s0 = make_float4(fmaxf(a2[q][0],0.f), fmaxf(a2[q][1],0.f),
                                fmaxf(a2[q][2],0.f), fmaxf(a2[q][3],0.f));
        float4 s1 = make_float4(fmaxf(a2[q][4],0.f), fmaxf(a2[q][5],0.f),
                                fmaxf(a2[q][6],0.f), fmaxf(a2[q][7],0.f));
        *(float4*)&r2s[el*128 + o0]     = s0;
        *(float4*)&r2s[el*128 + o0 + 4] = s1;
        *(float4*)&relu2T[(ebase + el)*128 + o0]     = s0;
        *(float4*)&relu2T[(ebase + el)*128 + o0 + 4] = s1;
    }
    __syncthreads();

    // ---- layer 0 (relu2 column from LDS; hfirst synthesized from h0) ----
    float* hs   = smem;        // 64
    float* wAs  = smem + 64;   // 48
    float* wBs  = smem + 112;  // 48
    float* sAB  = smem + 160;  // 2
    float* pU   = smem + 162;  // 2*128
    float* pV   = smem + 418;  // 2*128
    float* Us   = smem + 674;  // 128
    float* Vs   = smem + 802;  // 128
    float* pC   = smem + 930;  // 4*64
    float* aggs = smem + 1186; // 64
    float* gi   = smem + 1250; // 192
    float* gh   = smem + 1442; // 192 (ends 1634 < 6336, r2s untouched)

    const int r  = j % 3;
    const int q0 = j + j/3;

    if (tid < 64) hs[tid] = (tid < 32) ? h0[bj*32 + tid] : 0.f;
    else if (tid < 112){
        int i = tid - 64;
        int node = base + i;
        float gv = g[(size_t)node*48 + j];
        float ha = (q0   < 32) ? h0[node*32 + q0]     : 0.f;
        float hb = (q0+1 < 32) ? h0[node*32 + q0 + 1] : 0.f;
        wAs[i] = gv * ha;
        wBs[i] = gv * hb;
    }
    __syncthreads();
    if (tid < 2){
        const float* src = tid ? wBs : wAs;
        float s = 0.f;
        for (int i = 0; i < 48; i++) s += src[i];
        sAB[tid] = s;
    }
    {   // U/V partials (same 2x24 order as verified kernel)
        int c = tid & 127, half = tid >> 7;
        const float* rb = r2s + c;
        float aU = 0.f, aV = 0.f;
        for (int ii = 0; ii < 24; ii++){
            int i = half*24 + ii;
            float v = rb[i*128];
            aU += wAs[i]*v; aV += wBs[i]*v;
        }
        pU[half*128 + c] = aU; pV[half*128 + c] = aV;
    }
    __syncthreads();
    if (tid < 128){ Us[tid] = pU[tid] + pU[128 + tid]; }
    else { int c = tid - 128; Vs[c] = pV[c] + pV[128 + c]; }
    __syncthreads();
    {   // agg = U@A_r + V@B_r
        int m = tid & 63, cg2 = tid >> 6;
        const float* Arp = A  + r*8192 + m;
        const float* Brp = Bm + r*8192 + m;
        float a = 0.f;
        for (int cc = 0; cc < 32; cc++){
            int c = cg2*32 + cc;
            a += Us[c]*Arp[c*64] + Vs[c]*Brp[c*64];
        }
        pC[cg2*64 + m] = a;
    }
    __syncthreads();
    if (tid < 64){
        aggs[tid] = pC[tid] + pC[64+tid] + pC[128+tid] + pC[192+tid]
                  + sAB[0]*Ab[r*64 + tid] + sAB[1]*Bb[r*64 + tid];
    }
    __syncthreads();
    if (tid < 192){
        float gacc = bih[tid], hacc = bhh[tid];
        for (int k = 0; k < 64; k++){
            gacc += aggs[k] * wihT[k*192 + tid];
            hacc += hs[k]   * whhT[k*192 + tid];
        }
        gi[tid] = gacc; gh[tid] = hacc;
    }
    __syncthreads();
    if (tid < 64){
        float rr = sigmoidf_(gi[tid] + gh[tid]);
        float zz = sigmoidf_(gi[64+tid] + gh[64+tid]);
        float nn = tanhf(gi[128+tid] + rr*gh[128+tid]);
        float hnew = (1.f - zz)*nn + zz*hs[tid];
        hout[(size_t)bj*64 + tid] = mask[bj] * hnew;
    }
}

// ---------------------------------------------------------------------------
// K2: message-passing layer; relu2T read is block-contiguous (24 KB stream).
// ---------------------------------------------------------------------------
__global__ __launch_bounds__(256) void k_layer(
    const float* __restrict__ hin, float* __restrict__ hout,
    const float* __restrict__ relu2T,
    const float* __restrict__ A, const float* __restrict__ Bm,
    const float* __restrict__ Ab, const float* __restrict__ Bb,
    const float* __restrict__ g, const float* __restrict__ mask,
    const float* __restrict__ wihT, const float* __restrict__ whhT,
    const float* __restrict__ bih, const float* __restrict__ bhh)
{
    int bj = blockIdx.x;
    int b = bj / 48, j = bj - b*48;
    int r = j % 3;
    int p0 = j + j/3;
    int tid = threadIdx.x;
    int base = b*48;
    __shared__ float hs[64], wAs[48], wBs[48];
    __shared__ float pU[2][128], pV[2][128];
    __shared__ float Us[128], Vs[128];
    __shared__ float pC[4][64];
    __shared__ float sAB[2];
    __shared__ float aggs[64], gi[192], gh[192];

    if (tid < 64) hs[tid] = hin[(size_t)bj*64 + tid];
    else if (tid < 112){
        int i = tid - 64;
        int node = base + i;
        float gv = g[(size_t)node*48 + j];
        wAs[i] = gv * hin[(size_t)node*64 + p0];
        wBs[i] = gv * hin[(size_t)node*64 + p0 + 1];
    }
    __syncthreads();
    if (tid < 2){
        const float* src = tid ? wBs : wAs;
        float s = 0.f;
        for (int i = 0; i < 48; i++) s += src[i];
        sAB[tid] = s;
    }
    {
        int c = tid & 127, half = tid >> 7;
        const float* r2b = relu2T + (size_t)bj*6144 + c;   // i-stride 128
        float aU = 0.f, aV = 0.f;
        for (int ii = 0; ii < 24; ii++){
            int i = half*24 + ii;
            float v = r2b[i*128];
            aU += wAs[i]*v; aV += wBs[i]*v;
        }
        pU[half][c] = aU; pV[half][c] = aV;
    }
    __syncthreads();
    if (tid < 128){ Us[tid] = pU[0][tid] + pU[1][tid]; Vs[tid] = pV[0][tid] + pV[1][tid]; }
    __syncthreads();
    {
        int m = tid & 63, cg = tid >> 6;
        const float* Arp = A  + r*8192 + m;
        const float* Brp = Bm + r*8192 + m;
        float a = 0.f;
        for (int cc = 0; cc < 32; cc++){
            int c = cg*32 + cc;
            a += Us[c]*Arp[c*64] + Vs[c]*Brp[c*64];
        }
        pC[cg][m] = a;
    }
    __syncthreads();
    if (tid < 64){
        aggs[tid] = pC[0][tid] + pC[1][tid] + pC[2][tid] + pC[3][tid]
                  + sAB[0]*Ab[r*64 + tid] + sAB[1]*Bb[r*64 + tid];
    }
    __syncthreads();
    if (tid < 192){
        float gacc = bih[tid], hacc = bhh[tid];
        for (int k = 0; k < 64; k++){
            gacc += aggs[k] * wihT[k*192 + tid];
            hacc += hs[k]   * whhT[k*192 + tid];
        }
        gi[tid] = gacc; gh[tid] = hacc;
    }
    __syncthreads();
    if (tid < 64){
        float rr = sigmoidf_(gi[tid] + gh[tid]);
        float zz = sigmoidf_(gi[64+tid] + gh[64+tid]);
        float nn = tanhf(gi[128+tid] + rr*gh[128+tid]);
        float hnew = (1.f - zz)*nn + zz*hs[tid];
        hout[(size_t)bj*64 + tid] = mask[bj] * hnew;
    }
}

// ---------------------------------------------------------------------------
// k_read: readout, 192 blocks (16 batches x 12 groups of 4 nodes), 256 thr.
// (verified round-0 structure)
// ---------------------------------------------------------------------------
__device__ __forceinline__ void rd_layer(
    const float* __restrict__ Xs, const float* __restrict__ W,
    const float* __restrict__ bias, float* __restrict__ Ys,
    int dim, int o, int ng, bool do_relu)
{
    float a0 = bias[o];
    float a1 = a0;
    for (int i = 0; i < dim; i += 4){
        float w0 = W[(size_t)(i+0)*128 + o];
        float w1 = W[(size_t)(i+1)*128 + o];
        float w2 = W[(size_t)(i+2)*128 + o];
        float w3 = W[(size_t)(i+3)*128 + o];
        const float4 x0 = *(const float4*)&Xs[ng*128 + i];
        const float4 x1 = *(const float4*)&Xs[(ng+2)*128 + i];
        a0 += x0.x*w0 + x0.y*w1 + x0.z*w2 + x0.w*w3;
        a1 += x1.x*w0 + x1.y*w1 + x1.z*w2 + x1.w*w3;
    }
    if (do_relu){ a0 = fmaxf(a0, 0.f); a1 = fmaxf(a1, 0.f); }
    Ys[ng*128 + o] = a0;
    Ys[(ng+2)*128 + o] = a1;
}

__global__ __launch_bounds__(256) void k_read(
    const float* __restrict__ hfirst, const float* __restrict__ hT,
    const float* __restrict__ mask,
    const float* __restrict__ w00, const float* __restrict__ b00,
    const float* __restrict__ w01, const float* __restrict__ b01,
    const float* __restrict__ w02, const float* __restrict__ b02,
    const float* __restrict__ w10, const float* __restrict__ b10,
    const float* __restrict__ w11, const float* __restrict__ b11,
    const float* __restrict__ w12, const float* __restrict__ b12,
    float* __restrict__ partial)
{
    __shared__ __align__(16) float xs[4*128];
    __shared__ __align__(16) float ys[4*128];
    __shared__ __align__(16) float zs[4*128];
    __shared__ __align__(16) float os0[4*128];
    __shared__ float mS[4];
    int tid = threadIdx.x;
    int b = blockIdx.x / 12, gg = blockIdx.x - b*12;
    int node0 = b*48 + gg*4;
    int o = tid & 127, ng = tid >> 7;
    if (tid < 4) mS[tid] = mask[node0 + tid];
    for (int i = tid; i < 4*128; i += 256){
        int r = i >> 7, c = i & 127;
        xs[i] = (c < 64) ? hfirst[(size_t)(node0+r)*64 + c]
                         : hT[(size_t)(node0+r)*64 + (c - 64)];
    }
    __syncthreads();
    rd_layer(xs,      w00, b00, ys,  128, o, ng, true);  __syncthreads();
    rd_layer(ys,      w01, b01, zs,  128, o, ng, true);  __syncthreads();
    rd_layer(zs,      w02, b02, os0, 128, o, ng, false); __syncthreads();
    rd_layer(xs + 64, w10, b10, ys,  64,  o, ng, true);  __syncthreads();
    rd_layer(ys,      w11, b11, zs,  128, o, ng, true);  __syncthreads();
    {
        float a0 = b12[o];
        float a1 = a0;
        for (int i = 0; i < 128; i += 4){
            float w0 = w12[(size_t)(i+0)*128 + o];
            float w1 = w12[(size_t)(i+1)*128 + o];
            float w2 = w12[(size_t)(i+2)*128 + o];
            float w3 = w12[(size_t)(i+3)*128 + o];
            const float4 x0 = *(const float4*)&zs[ng*128 + i];
            const float4 x1 = *(const float4*)&zs[(ng+2)*128 + i];
            a0 += x0.x*w0 + x0.y*w1 + x0.z*w2 + x0.w*w3;
            a1 += x1.x*w0 + x1.y*w1 + x1.z*w2 + x1.w*w3;
        }
        float s = mS[ng]   * os0[ng*128 + o]     * a0
                + mS[ng+2] * os0[(ng+2)*128 + o] * a1;
        __syncthreads();
        ys[ng*128 + o] = s;
    }
    __syncthreads();
    if (tid < 128)
        partial[(size_t)blockIdx.x*128 + tid] = ys[tid] + ys[128 + tid];
}

// ---------------------------------------------------------------------------
// k_final: reduce 12 partials per batch + sigmoid
// ---------------------------------------------------------------------------
__global__ void k_final(const float* __restrict__ partial, float* __restrict__ out)
{
    int idx = blockIdx.x*256 + threadIdx.x;
    if (idx < B_*128){
        int b = idx >> 7, t = idx & 127;
        float s = 0.f;
        for (int c = 0; c < 12; c++) s += partial[(size_t)(b*12 + c)*128 + t];
        out[idx] = 1.0f / (1.0f + expf(-s));
    }
}

// ---------------------------------------------------------------------------
extern "C" void kernel_launch(void* const* d_in, const int* in_sizes, int n_in,
                              void* d_out, int out_size, void* d_ws, size_t ws_size,
                              hipStream_t stream)
{
    (void)in_sizes; (void)n_in; (void)out_size; (void)ws_size;
    const float* g    = (const float*)d_in[0];
    const float* h0   = (const float*)d_in[1];
    const float* e    = (const float*)d_in[2];
    const float* mw0  = (const float*)d_in[3];
    const float* mb0  = (const float*)d_in[4];
    const float* mw1  = (const float*)d_in[5];
    const float* mb1  = (const float*)d_in[6];
    const float* mw2  = (const float*)d_in[7];
    const float* mb2  = (const float*)d_in[8];
    const float* wih  = (const float*)d_in[9];
    const float* whh  = (const float*)d_in[10];
    const float* bih  = (const float*)d_in[11];
    const float* bhh  = (const float*)d_in[12];
    const float* r0w0 = (const float*)d_in[13];
    const float* r0b0 = (const float*)d_in[14];
    const float* r0w1 = (const float*)d_in[15];
    const float* r0b1 = (const float*)d_in[16];
    const float* r0w2 = (const float*)d_in[17];
    const float* r0b2 = (const float*)d_in[18];
    const float* r1w0 = (const float*)d_in[19];
    const float* r1b0 = (const float*)d_in[20];
    const float* r1w1 = (const float*)d_in[21];
    const float* r1b1 = (const float*)d_in[22];
    const float* r1w2 = (const float*)d_in[23];
    const float* r1b2 = (const float*)d_in[24];
    float* out = (float*)d_out;

    float* ws     = (float*)d_ws;
    float* A      = ws;                  // 3*128*64   = 24576
    float* Bm     = A      + 24576;      //              24576
    float* Ab     = Bm     + 24576;      // 3*64       = 192
    float* Bb     = Ab     + 192;        //              192
    float* hfirst = Bb     + 192;        // 768*64     = 49152
    float* hA     = hfirst + 49152;      //              49152
    float* hB     = hA     + 49152;      //              49152
    float* mask   = hB     + 49152;      //              768
    float* wihT   = mask   + 768;        // 64*192     = 12288
    float* whhT   = wihT   + 12288;      //              12288
    float* part   = whhT   + 12288;      // 192*128    = 24576
    float* eT     = part   + 24576;      // 36864*16   = 589824
    float* relu2T = eT     + 589824;     // 36864*128  = 4718592
    // total ~ 5.6M floats = 21.5 MiB

    k_prep<<<961, 256, 0, stream>>>(mw2, mb2, h0, wih, whh, e,
                                    A, Bm, Ab, Bb, hfirst, mask, wihT, whhT, eT);
    k1_mlp_l0<<<768, 256, 0, stream>>>(eT, mw0, mb0, mw1, mb1, g, h0, mask,
                                       A, Bm, Ab, Bb, wihT, whhT, bih, bhh,
                                       relu2T, hA);
    k_layer<<<768, 256, 0, stream>>>(hA, hB, relu2T, A, Bm, Ab, Bb, g, mask,
                                     wihT, whhT, bih, bhh);
    k_layer<<<768, 256, 0, stream>>>(hB, hA, relu2T, A, Bm, Ab, Bb, g, mask,
                                     wihT, whhT, bih, bhh);
    k_read<<<192, 256, 0, stream>>>(hfirst, hA, mask,
                                    r0w0, r0b0, r0w1, r0b1, r0w2, r0b2,
                                    r1w0, r1b0, r1w1, r1b1, r1w2, r1b2, part);
    k_final<<<8, 256, 0, stream>>>(part, out);
}